// Round 11
// baseline (220.441 us; speedup 1.0000x reference)
//
#include <hip/hip_runtime.h>

// FullNN: per-atom MLP (FEAT=64 -> tanh(HID=64) -> 1) + segment-sum over 32768 structs.
// Round 11: eight structures (rounds 3-10) all pinned at 202-240us with no pipe
// saturated, across occupancy 36-56%, prefetch depth 0-2, LDS/reg staging, atomics
// present/absent. Invariant: the 768MB x stream through the 256MB L3 at ~50% hit
// (FETCH = exactly half the stream every round) delivering ~3.8 TB/s combined.
// Theory: mixed L3-hit/HBM-miss streaming with allocation churn is the ceiling.
// Fix: NONTEMPORAL loads (nt bit) for x + idx -- no L2/L3 allocation, pure HBM
// streaming path. Also: atomic issued last in the loop body so the in-order vmcnt
// queue never makes a load-consume wait drain an atomic. Grid (683,3) = 8 blk/CU.
//
// MFMA mfma_f32_16x16x32_bf16, swapped H^T = W1^T @ x^T (learn_hip m89/m97):
//   A: row=lane&15, k=(lane>>4)*8+i -> W1^T frag (from LDS, shared by 4 waves)
//   B: col=lane&15 (= atom), k=(lane>>4)*8+i -> x^T frag (registers)
//   D: col=lane&15 (= atom), j=16t+kg*4+r    -> in-lane W2 reduce, 2 shfls

typedef __attribute__((ext_vector_type(8))) short bf16x8;
typedef __attribute__((ext_vector_type(4))) float f32x4;

struct ElemPtrs {
    const float* x;
    const int*   idx;
    const float* W1;
    const float* b1;
    const float* W2;
    const float* b2;
};
struct Params {
    ElemPtrs e[3];
    int n_tiles;   // atoms / 16
};

__device__ __forceinline__ short f2bf(float f) {
    __bf16 h = (__bf16)f;           // hardware RNE; pairs into v_cvt_pk_bf16_f32
    return __builtin_bit_cast(short, h);
}

__device__ __forceinline__ float fast_tanh(float v) {
    v = __builtin_amdgcn_fmed3f(v, -10.0f, 10.0f);
    float t = __builtin_amdgcn_exp2f(v * 2.8853900817779268f); // 2^(2v*log2 e)
    return (t - 1.0f) * __builtin_amdgcn_rcpf(t + 1.0f);
}

// nontemporal 16B load of an ext-vector float4 (emits global_load_dwordx4 ... nt)
__device__ __forceinline__ f32x4 ntload4(const float* p) {
    return __builtin_nontemporal_load(reinterpret_cast<const f32x4*>(p));
}

__global__ __launch_bounds__(256, 4) void atom_mlp(Params p, float* __restrict__ out)
{
    const ElemPtrs ep = p.e[blockIdx.y];   // uniform index -> scalar code

    // W1^T fragments, shared by the block's 4 waves: [frag fid=s*4+t][lane] x 16B
    __shared__ bf16x8 Wlds[8][64];

    const int tid  = threadIdx.x;
    const int lane = tid & 63;
    const int col  = lane & 15;    // atom within tile
    const int kg   = lane >> 4;    // k-group

    // ---- cooperative stage of W1^T fragments ----
    {
        const int wv = tid >> 6;
        #pragma unroll
        for (int q = 0; q < 2; ++q) {
            const int fid = wv * 2 + q;
            const int s = fid >> 2, t = fid & 3;
            bf16x8 w;
            #pragma unroll
            for (int i = 0; i < 8; ++i)
                w[i] = f2bf(ep.W1[(s * 32 + kg * 8 + i) * 64 + 16 * t + col]);
            Wlds[fid][lane] = w;
        }
    }

    // per-lane b1 (MFMA C-init) and W2, j = 16t + kg*4 + r
    f32x4 b1c[4], w2c[4];
    #pragma unroll
    for (int t = 0; t < 4; ++t)
        #pragma unroll
        for (int r = 0; r < 4; ++r) {
            b1c[t][r] = ep.b1[16 * t + kg * 4 + r];
            w2c[t][r] = ep.W2[16 * t + kg * 4 + r];
        }
    const float b2v = ep.b2[0];

    __syncthreads();

    // 32-bit LDS byte address of this lane's frag 0 (frag fid at +fid*1024)
    typedef __attribute__((address_space(3))) const void* as3cv;
    const unsigned waddr = (unsigned)(size_t)(as3cv)&Wlds[0][lane];

    const int wid    = (blockIdx.x * 256 + tid) >> 6;
    const int nwaves = (gridDim.x * 256) >> 6;
    const size_t xoff = (size_t)col * 64 + (size_t)kg * 8;

    int tile = wid;
    if (tile >= p.n_tiles) return;          // wave-uniform

    // prefetch first tile (nontemporal)
    const float* xp = ep.x + (size_t)tile * 1024 + xoff;
    f32x4 c0 = ntload4(xp);
    f32x4 c1 = ntload4(xp + 4);
    f32x4 c2 = ntload4(xp + 32);
    f32x4 c3 = ntload4(xp + 36);
    int ia = __builtin_nontemporal_load(ep.idx + tile * 16 + col);

    while (true) {
        // ---- issue next tile's loads FIRST (oldest in vmcnt queue) ----
        const int nxt = tile + nwaves;
        const bool have = (nxt < p.n_tiles);   // wave-uniform
        f32x4 n0, n1, n2, n3;
        int ib;
        if (have) {
            const float* xn = ep.x + (size_t)nxt * 1024 + xoff;
            n0 = ntload4(xn);
            n1 = ntload4(xn + 4);
            n2 = ntload4(xn + 32);
            n3 = ntload4(xn + 36);
            ib = __builtin_nontemporal_load(ep.idx + nxt * 16 + col);
        }

        // ---- convert current tile to bf16 B-fragments ----
        bf16x8 X0, X1;
        X0[0]=f2bf(c0[0]); X0[1]=f2bf(c0[1]); X0[2]=f2bf(c0[2]); X0[3]=f2bf(c0[3]);
        X0[4]=f2bf(c1[0]); X0[5]=f2bf(c1[1]); X0[6]=f2bf(c1[2]); X0[7]=f2bf(c1[3]);
        X1[0]=f2bf(c2[0]); X1[1]=f2bf(c2[1]); X1[2]=f2bf(c2[2]); X1[3]=f2bf(c2[3]);
        X1[4]=f2bf(c3[0]); X1[5]=f2bf(c3[1]); X1[6]=f2bf(c3[2]); X1[7]=f2bf(c3[3]);

        // ---- frag group 0 (fids 0..3) from LDS, then 4 MFMAs on X0 ----
        bf16x8 w0, w1, w2, w3;
        asm volatile("ds_read_b128 %0, %1 offset:0"    : "=v"(w0) : "v"(waddr));
        asm volatile("ds_read_b128 %0, %1 offset:1024" : "=v"(w1) : "v"(waddr));
        asm volatile("ds_read_b128 %0, %1 offset:2048" : "=v"(w2) : "v"(waddr));
        asm volatile("ds_read_b128 %0, %1 offset:3072" : "=v"(w3) : "v"(waddr));
        asm volatile("s_waitcnt lgkmcnt(0)" ::: "memory");
        __builtin_amdgcn_sched_barrier(0);

        f32x4 a0 = __builtin_amdgcn_mfma_f32_16x16x32_bf16(w0, X0, b1c[0], 0, 0, 0);
        f32x4 a1 = __builtin_amdgcn_mfma_f32_16x16x32_bf16(w1, X0, b1c[1], 0, 0, 0);
        f32x4 a2 = __builtin_amdgcn_mfma_f32_16x16x32_bf16(w2, X0, b1c[2], 0, 0, 0);
        f32x4 a3 = __builtin_amdgcn_mfma_f32_16x16x32_bf16(w3, X0, b1c[3], 0, 0, 0);

        // ---- frag group 1 (fids 4..7) from LDS, then 4 MFMAs on X1 ----
        asm volatile("ds_read_b128 %0, %1 offset:4096" : "=v"(w0) : "v"(waddr));
        asm volatile("ds_read_b128 %0, %1 offset:5120" : "=v"(w1) : "v"(waddr));
        asm volatile("ds_read_b128 %0, %1 offset:6144" : "=v"(w2) : "v"(waddr));
        asm volatile("ds_read_b128 %0, %1 offset:7168" : "=v"(w3) : "v"(waddr));
        asm volatile("s_waitcnt lgkmcnt(0)" ::: "memory");
        __builtin_amdgcn_sched_barrier(0);

        a0 = __builtin_amdgcn_mfma_f32_16x16x32_bf16(w0, X1, a0, 0, 0, 0);
        a1 = __builtin_amdgcn_mfma_f32_16x16x32_bf16(w1, X1, a1, 0, 0, 0);
        a2 = __builtin_amdgcn_mfma_f32_16x16x32_bf16(w2, X1, a2, 0, 0, 0);
        a3 = __builtin_amdgcn_mfma_f32_16x16x32_bf16(w3, X1, a3, 0, 0, 0);

        // epilogue: e = sum_j tanh(H[atom][j]) * W2[j], fully in-lane
        float ev;
        ev  = fast_tanh(a0[0]) * w2c[0][0];
        ev += fast_tanh(a0[1]) * w2c[0][1];
        ev += fast_tanh(a0[2]) * w2c[0][2];
        ev += fast_tanh(a0[3]) * w2c[0][3];
        ev += fast_tanh(a1[0]) * w2c[1][0];
        ev += fast_tanh(a1[1]) * w2c[1][1];
        ev += fast_tanh(a1[2]) * w2c[1][2];
        ev += fast_tanh(a1[3]) * w2c[1][3];
        ev += fast_tanh(a2[0]) * w2c[2][0];
        ev += fast_tanh(a2[1]) * w2c[2][1];
        ev += fast_tanh(a2[2]) * w2c[2][2];
        ev += fast_tanh(a2[3]) * w2c[2][3];
        ev += fast_tanh(a3[0]) * w2c[3][0];
        ev += fast_tanh(a3[1]) * w2c[3][1];
        ev += fast_tanh(a3[2]) * w2c[3][2];
        ev += fast_tanh(a3[3]) * w2c[3][3];
        ev += __shfl_xor(ev, 16);
        ev += __shfl_xor(ev, 32);

        // atomic LAST: newest in the vmcnt queue; next iteration's load-consume
        // waits (counted) complete before it and never drain it.
        if (lane < 16) atomicAdd(&out[ia], ev + b2v);

        if (!have) break;
        c0 = n0; c1 = n1; c2 = n2; c3 = n3; ia = ib;
        tile = nxt;
    }
}

extern "C" void kernel_launch(void* const* d_in, const int* in_sizes, int n_in,
                              void* d_out, int out_size, void* d_ws, size_t ws_size,
                              hipStream_t stream) {
    Params p;
    for (int e = 0; e < 3; ++e) {
        p.e[e].x   = (const float*)d_in[6 * e + 0];
        p.e[e].idx = (const int*)  d_in[6 * e + 1];
        p.e[e].W1  = (const float*)d_in[6 * e + 2];
        p.e[e].b1  = (const float*)d_in[6 * e + 3];
        p.e[e].W2  = (const float*)d_in[6 * e + 4];
        p.e[e].b2  = (const float*)d_in[6 * e + 5];
    }
    const int n_atoms = in_sizes[0] / 64;
    p.n_tiles = n_atoms / 16;   // 62,500

    float* out = (float*)d_out;
    // d_out is poisoned (0xAA) before timing and NOT re-zeroed between replays.
    hipMemsetAsync(out, 0, (size_t)out_size * sizeof(float), stream);

    // 683x3 = 2049 blocks ~ exactly 8 blocks/CU: whole grid co-resident.
    dim3 grid(683, 3);
    atom_mlp<<<grid, 256, 0, stream>>>(p, out);
}

// Round 12
// 182.362 us; speedup vs baseline: 1.2088x; 1.2088x over previous
//
#include <hip/hip_runtime.h>

// FullNN: per-atom MLP (FEAT=64 -> tanh(HID=64) -> 1) + segment-sum over 32768 structs.
// Round 12: rounds 8-11 establish the invariant -- delivered read BW pinned at
// ~3.75 TB/s = waves/CU (16) x in-flight-at-stall (4KB) / latency (~1.4us). Every
// earlier "prefetch" collapsed to 4KB outstanding at the wait point (convert-at-load,
// wait-at-copy, drained vmcnt). Fix: depth-2 ping-pong, statically named slots,
// with converts FIRST (counted vmcnt leaves the other tile + refill in flight),
// refill issued immediately after, compute after that. At stall: 10 loads (8KB)
// + 2 atomics outstanding per wave -> 128KB/CU in flight, 2.5x round-10.
//
// MFMA mfma_f32_16x16x32_bf16, swapped H^T = W1^T @ x^T (learn_hip m89/m97):
//   A: row=lane&15, k=(lane>>4)*8+i -> W1^T frag (LDS, shared by 4 waves)
//   B: col=lane&15 (= atom), k=(lane>>4)*8+i -> x^T frag (registers)
//   D: col=lane&15 (= atom), j=16t+kg*4+r    -> in-lane W2 reduce, 2 shfls

typedef __attribute__((ext_vector_type(8))) short bf16x8;
typedef __attribute__((ext_vector_type(4))) float f32x4;

struct ElemPtrs {
    const float* x;
    const int*   idx;
    const float* W1;
    const float* b1;
    const float* W2;
    const float* b2;
};
struct Params {
    ElemPtrs e[3];
    int n_tiles;   // atoms / 16
};

__device__ __forceinline__ short f2bf(float f) {
    __bf16 h = (__bf16)f;           // hardware RNE; pairs into v_cvt_pk_bf16_f32
    return __builtin_bit_cast(short, h);
}

__device__ __forceinline__ float fast_tanh(float v) {
    v = __builtin_amdgcn_fmed3f(v, -10.0f, 10.0f);
    float t = __builtin_amdgcn_exp2f(v * 2.8853900817779268f); // 2^(2v*log2 e)
    return (t - 1.0f) * __builtin_amdgcn_rcpf(t + 1.0f);
}

__global__ __launch_bounds__(256, 4) void atom_mlp(Params p, float* __restrict__ out)
{
    const ElemPtrs ep = p.e[blockIdx.y];   // uniform index -> scalar code

    // W1^T fragments, shared by the block's 4 waves: [frag fid=s*4+t][lane] x 16B
    __shared__ bf16x8 Wlds[8][64];

    const int tid  = threadIdx.x;
    const int lane = tid & 63;
    const int col  = lane & 15;    // atom within tile
    const int kg   = lane >> 4;    // k-group

    // ---- cooperative stage of W1^T fragments ----
    {
        const int wv = tid >> 6;
        #pragma unroll
        for (int q = 0; q < 2; ++q) {
            const int fid = wv * 2 + q;
            const int s = fid >> 2, t = fid & 3;
            bf16x8 w;
            #pragma unroll
            for (int i = 0; i < 8; ++i)
                w[i] = f2bf(ep.W1[(s * 32 + kg * 8 + i) * 64 + 16 * t + col]);
            Wlds[fid][lane] = w;
        }
    }

    // per-lane b1 (MFMA C-init) and W2, j = 16t + kg*4 + r
    f32x4 b1c[4], w2c[4];
    #pragma unroll
    for (int t = 0; t < 4; ++t)
        #pragma unroll
        for (int r = 0; r < 4; ++r) {
            b1c[t][r] = ep.b1[16 * t + kg * 4 + r];
            w2c[t][r] = ep.W2[16 * t + kg * 4 + r];
        }
    const float b2v = ep.b2[0];

    __syncthreads();

    // 32-bit LDS byte address of this lane's frag 0 (frag fid at +fid*1024)
    typedef __attribute__((address_space(3))) const void* as3cv;
    const unsigned waddr = (unsigned)(size_t)(as3cv)&Wlds[0][lane];

    const int nt = p.n_tiles;
    const int wid = (blockIdx.x * 256 + tid) >> 6;
    const int nw  = (gridDim.x * 256) >> 6;
    const long xoff = (long)col * 64 + (long)kg * 8;

    int tA = wid;
    if (tA >= nt) return;                  // wave-uniform

    // ---- prologue: fill both pipeline slots ----
    const float* xpA = ep.x + (long)tA * 1024 + xoff;
    const int*   ipA = ep.idx + tA * 16 + col;
    f32x4 cA0 = *reinterpret_cast<const f32x4*>(xpA);
    f32x4 cA1 = *reinterpret_cast<const f32x4*>(xpA + 4);
    f32x4 cA2 = *reinterpret_cast<const f32x4*>(xpA + 32);
    f32x4 cA3 = *reinterpret_cast<const f32x4*>(xpA + 36);
    int iaA = *ipA;

    int tB = tA + nw;
    bool liveB = (tB < nt);
    const float* xpB = xpA + (long)nw * 1024;
    const int*   ipB = ipA + nw * 16;
    f32x4 cB0, cB1, cB2, cB3;
    int iaB = 0;
    if (liveB) {
        cB0 = *reinterpret_cast<const f32x4*>(xpB);
        cB1 = *reinterpret_cast<const f32x4*>(xpB + 4);
        cB2 = *reinterpret_cast<const f32x4*>(xpB + 32);
        cB3 = *reinterpret_cast<const f32x4*>(xpB + 36);
        iaB = *ipB;
    }

    const long xstep = (long)2 * nw * 1024;
    const int  istep = 2 * nw * 16;
    bool liveA = true;
    (void)liveA;

    // one pipeline stage: convert slot, refill slot (t+2), W1-dsread + 8 MFMA,
    // tanh epilogue, atomic. Slots statically named (rule #20).
#define STAGE_BODY(C0, C1, C2, C3, IA, XP, IP, TT, LIVE_OTHER)                   \
    {                                                                            \
        /* converts first: compiler emits counted vmcnt leaving rest in flight */\
        bf16x8 X0, X1;                                                           \
        X0[0]=f2bf(C0[0]); X0[1]=f2bf(C0[1]); X0[2]=f2bf(C0[2]); X0[3]=f2bf(C0[3]); \
        X0[4]=f2bf(C1[0]); X0[5]=f2bf(C1[1]); X0[6]=f2bf(C1[2]); X0[7]=f2bf(C1[3]); \
        X1[0]=f2bf(C2[0]); X1[1]=f2bf(C2[1]); X1[2]=f2bf(C2[2]); X1[3]=f2bf(C2[3]); \
        X1[4]=f2bf(C3[0]); X1[5]=f2bf(C3[1]); X1[6]=f2bf(C3[2]); X1[7]=f2bf(C3[3]); \
        const int iaCur = IA;                                                    \
        const int tN = (TT) + 2 * nw;                                            \
        const bool haveN = (tN < nt);           /* wave-uniform */               \
        if (haveN) {                                                             \
            XP += xstep; IP += istep;                                            \
            C0 = *reinterpret_cast<const f32x4*>(XP);                            \
            C1 = *reinterpret_cast<const f32x4*>(XP + 4);                        \
            C2 = *reinterpret_cast<const f32x4*>(XP + 32);                       \
            C3 = *reinterpret_cast<const f32x4*>(XP + 36);                       \
            IA = *IP;                                                            \
        }                                                                        \
        __builtin_amdgcn_sched_barrier(0);      /* pin refill issue-early */     \
        bf16x8 w0, w1, w2, w3;                                                   \
        asm volatile("ds_read_b128 %0, %1 offset:0"    : "=v"(w0) : "v"(waddr)); \
        asm volatile("ds_read_b128 %0, %1 offset:1024" : "=v"(w1) : "v"(waddr)); \
        asm volatile("ds_read_b128 %0, %1 offset:2048" : "=v"(w2) : "v"(waddr)); \
        asm volatile("ds_read_b128 %0, %1 offset:3072" : "=v"(w3) : "v"(waddr)); \
        asm volatile("s_waitcnt lgkmcnt(0)" ::: "memory");                       \
        __builtin_amdgcn_sched_barrier(0);                                       \
        f32x4 a0 = __builtin_amdgcn_mfma_f32_16x16x32_bf16(w0, X0, b1c[0], 0, 0, 0); \
        f32x4 a1 = __builtin_amdgcn_mfma_f32_16x16x32_bf16(w1, X0, b1c[1], 0, 0, 0); \
        f32x4 a2 = __builtin_amdgcn_mfma_f32_16x16x32_bf16(w2, X0, b1c[2], 0, 0, 0); \
        f32x4 a3 = __builtin_amdgcn_mfma_f32_16x16x32_bf16(w3, X0, b1c[3], 0, 0, 0); \
        asm volatile("ds_read_b128 %0, %1 offset:4096" : "=v"(w0) : "v"(waddr)); \
        asm volatile("ds_read_b128 %0, %1 offset:5120" : "=v"(w1) : "v"(waddr)); \
        asm volatile("ds_read_b128 %0, %1 offset:6144" : "=v"(w2) : "v"(waddr)); \
        asm volatile("ds_read_b128 %0, %1 offset:7168" : "=v"(w3) : "v"(waddr)); \
        asm volatile("s_waitcnt lgkmcnt(0)" ::: "memory");                       \
        __builtin_amdgcn_sched_barrier(0);                                       \
        a0 = __builtin_amdgcn_mfma_f32_16x16x32_bf16(w0, X1, a0, 0, 0, 0);       \
        a1 = __builtin_amdgcn_mfma_f32_16x16x32_bf16(w1, X1, a1, 0, 0, 0);       \
        a2 = __builtin_amdgcn_mfma_f32_16x16x32_bf16(w2, X1, a2, 0, 0, 0);       \
        a3 = __builtin_amdgcn_mfma_f32_16x16x32_bf16(w3, X1, a3, 0, 0, 0);       \
        float ev;                                                                \
        ev  = fast_tanh(a0[0]) * w2c[0][0];                                      \
        ev += fast_tanh(a0[1]) * w2c[0][1];                                      \
        ev += fast_tanh(a0[2]) * w2c[0][2];                                      \
        ev += fast_tanh(a0[3]) * w2c[0][3];                                      \
        ev += fast_tanh(a1[0]) * w2c[1][0];                                      \
        ev += fast_tanh(a1[1]) * w2c[1][1];                                      \
        ev += fast_tanh(a1[2]) * w2c[1][2];                                      \
        ev += fast_tanh(a1[3]) * w2c[1][3];                                      \
        ev += fast_tanh(a2[0]) * w2c[2][0];                                      \
        ev += fast_tanh(a2[1]) * w2c[2][1];                                      \
        ev += fast_tanh(a2[2]) * w2c[2][2];                                      \
        ev += fast_tanh(a2[3]) * w2c[2][3];                                      \
        ev += fast_tanh(a3[0]) * w2c[3][0];                                      \
        ev += fast_tanh(a3[1]) * w2c[3][1];                                      \
        ev += fast_tanh(a3[2]) * w2c[3][2];                                      \
        ev += fast_tanh(a3[3]) * w2c[3][3];                                      \
        ev += __shfl_xor(ev, 16);                                                \
        ev += __shfl_xor(ev, 32);                                                \
        if (lane < 16) atomicAdd(&out[iaCur], ev + b2v);  /* newest in vm queue */ \
        TT = tN;                                                                 \
        if (!(LIVE_OTHER)) goto done;                                            \
        LIVE_OTHER = (LIVE_OTHER);                                               \
    }

    {
        bool dummyTrue = true;
        (void)dummyTrue;
        while (true) {
            // ---- slot A ----
            {
                bf16x8 X0, X1;
                X0[0]=f2bf(cA0[0]); X0[1]=f2bf(cA0[1]); X0[2]=f2bf(cA0[2]); X0[3]=f2bf(cA0[3]);
                X0[4]=f2bf(cA1[0]); X0[5]=f2bf(cA1[1]); X0[6]=f2bf(cA1[2]); X0[7]=f2bf(cA1[3]);
                X1[0]=f2bf(cA2[0]); X1[1]=f2bf(cA2[1]); X1[2]=f2bf(cA2[2]); X1[3]=f2bf(cA2[3]);
                X1[4]=f2bf(cA3[0]); X1[5]=f2bf(cA3[1]); X1[6]=f2bf(cA3[2]); X1[7]=f2bf(cA3[3]);
                const int iaCur = iaA;
                const int tN = tA + 2 * nw;
                const bool haveN = (tN < nt);
                if (haveN) {
                    xpA += xstep; ipA += istep;
                    cA0 = *reinterpret_cast<const f32x4*>(xpA);
                    cA1 = *reinterpret_cast<const f32x4*>(xpA + 4);
                    cA2 = *reinterpret_cast<const f32x4*>(xpA + 32);
                    cA3 = *reinterpret_cast<const f32x4*>(xpA + 36);
                    iaA = *ipA;
                }
                __builtin_amdgcn_sched_barrier(0);
                bf16x8 w0, w1, w2, w3;
                asm volatile("ds_read_b128 %0, %1 offset:0"    : "=v"(w0) : "v"(waddr));
                asm volatile("ds_read_b128 %0, %1 offset:1024" : "=v"(w1) : "v"(waddr));
                asm volatile("ds_read_b128 %0, %1 offset:2048" : "=v"(w2) : "v"(waddr));
                asm volatile("ds_read_b128 %0, %1 offset:3072" : "=v"(w3) : "v"(waddr));
                asm volatile("s_waitcnt lgkmcnt(0)" ::: "memory");
                __builtin_amdgcn_sched_barrier(0);
                f32x4 a0 = __builtin_amdgcn_mfma_f32_16x16x32_bf16(w0, X0, b1c[0], 0, 0, 0);
                f32x4 a1 = __builtin_amdgcn_mfma_f32_16x16x32_bf16(w1, X0, b1c[1], 0, 0, 0);
                f32x4 a2 = __builtin_amdgcn_mfma_f32_16x16x32_bf16(w2, X0, b1c[2], 0, 0, 0);
                f32x4 a3 = __builtin_amdgcn_mfma_f32_16x16x32_bf16(w3, X0, b1c[3], 0, 0, 0);
                asm volatile("ds_read_b128 %0, %1 offset:4096" : "=v"(w0) : "v"(waddr));
                asm volatile("ds_read_b128 %0, %1 offset:5120" : "=v"(w1) : "v"(waddr));
                asm volatile("ds_read_b128 %0, %1 offset:6144" : "=v"(w2) : "v"(waddr));
                asm volatile("ds_read_b128 %0, %1 offset:7168" : "=v"(w3) : "v"(waddr));
                asm volatile("s_waitcnt lgkmcnt(0)" ::: "memory");
                __builtin_amdgcn_sched_barrier(0);
                a0 = __builtin_amdgcn_mfma_f32_16x16x32_bf16(w0, X1, a0, 0, 0, 0);
                a1 = __builtin_amdgcn_mfma_f32_16x16x32_bf16(w1, X1, a1, 0, 0, 0);
                a2 = __builtin_amdgcn_mfma_f32_16x16x32_bf16(w2, X1, a2, 0, 0, 0);
                a3 = __builtin_amdgcn_mfma_f32_16x16x32_bf16(w3, X1, a3, 0, 0, 0);
                float ev;
                ev  = fast_tanh(a0[0]) * w2c[0][0];
                ev += fast_tanh(a0[1]) * w2c[0][1];
                ev += fast_tanh(a0[2]) * w2c[0][2];
                ev += fast_tanh(a0[3]) * w2c[0][3];
                ev += fast_tanh(a1[0]) * w2c[1][0];
                ev += fast_tanh(a1[1]) * w2c[1][1];
                ev += fast_tanh(a1[2]) * w2c[1][2];
                ev += fast_tanh(a1[3]) * w2c[1][3];
                ev += fast_tanh(a2[0]) * w2c[2][0];
                ev += fast_tanh(a2[1]) * w2c[2][1];
                ev += fast_tanh(a2[2]) * w2c[2][2];
                ev += fast_tanh(a2[3]) * w2c[2][3];
                ev += fast_tanh(a3[0]) * w2c[3][0];
                ev += fast_tanh(a3[1]) * w2c[3][1];
                ev += fast_tanh(a3[2]) * w2c[3][2];
                ev += fast_tanh(a3[3]) * w2c[3][3];
                ev += __shfl_xor(ev, 16);
                ev += __shfl_xor(ev, 32);
                if (lane < 16) atomicAdd(&out[iaCur], ev + b2v);
                tA = tN;
                liveA = haveN;
            }
            if (!liveB) break;

            // ---- slot B ----
            {
                bf16x8 X0, X1;
                X0[0]=f2bf(cB0[0]); X0[1]=f2bf(cB0[1]); X0[2]=f2bf(cB0[2]); X0[3]=f2bf(cB0[3]);
                X0[4]=f2bf(cB1[0]); X0[5]=f2bf(cB1[1]); X0[6]=f2bf(cB1[2]); X0[7]=f2bf(cB1[3]);
                X1[0]=f2bf(cB2[0]); X1[1]=f2bf(cB2[1]); X1[2]=f2bf(cB2[2]); X1[3]=f2bf(cB2[3]);
                X1[4]=f2bf(cB3[0]); X1[5]=f2bf(cB3[1]); X1[6]=f2bf(cB3[2]); X1[7]=f2bf(cB3[3]);
                const int iaCur = iaB;
                const int tN = tB + 2 * nw;
                const bool haveN = (tN < nt);
                if (haveN) {
                    xpB += xstep; ipB += istep;
                    cB0 = *reinterpret_cast<const f32x4*>(xpB);
                    cB1 = *reinterpret_cast<const f32x4*>(xpB + 4);
                    cB2 = *reinterpret_cast<const f32x4*>(xpB + 32);
                    cB3 = *reinterpret_cast<const f32x4*>(xpB + 36);
                    iaB = *ipB;
                }
                __builtin_amdgcn_sched_barrier(0);
                bf16x8 w0, w1, w2, w3;
                asm volatile("ds_read_b128 %0, %1 offset:0"    : "=v"(w0) : "v"(waddr));
                asm volatile("ds_read_b128 %0, %1 offset:1024" : "=v"(w1) : "v"(waddr));
                asm volatile("ds_read_b128 %0, %1 offset:2048" : "=v"(w2) : "v"(waddr));
                asm volatile("ds_read_b128 %0, %1 offset:3072" : "=v"(w3) : "v"(waddr));
                asm volatile("s_waitcnt lgkmcnt(0)" ::: "memory");
                __builtin_amdgcn_sched_barrier(0);
                f32x4 a0 = __builtin_amdgcn_mfma_f32_16x16x32_bf16(w0, X0, b1c[0], 0, 0, 0);
                f32x4 a1 = __builtin_amdgcn_mfma_f32_16x16x32_bf16(w1, X0, b1c[1], 0, 0, 0);
                f32x4 a2 = __builtin_amdgcn_mfma_f32_16x16x32_bf16(w2, X0, b1c[2], 0, 0, 0);
                f32x4 a3 = __builtin_amdgcn_mfma_f32_16x16x32_bf16(w3, X0, b1c[3], 0, 0, 0);
                asm volatile("ds_read_b128 %0, %1 offset:4096" : "=v"(w0) : "v"(waddr));
                asm volatile("ds_read_b128 %0, %1 offset:5120" : "=v"(w1) : "v"(waddr));
                asm volatile("ds_read_b128 %0, %1 offset:6144" : "=v"(w2) : "v"(waddr));
                asm volatile("ds_read_b128 %0, %1 offset:7168" : "=v"(w3) : "v"(waddr));
                asm volatile("s_waitcnt lgkmcnt(0)" ::: "memory");
                __builtin_amdgcn_sched_barrier(0);
                a0 = __builtin_amdgcn_mfma_f32_16x16x32_bf16(w0, X1, a0, 0, 0, 0);
                a1 = __builtin_amdgcn_mfma_f32_16x16x32_bf16(w1, X1, a1, 0, 0, 0);
                a2 = __builtin_amdgcn_mfma_f32_16x16x32_bf16(w2, X1, a2, 0, 0, 0);
                a3 = __builtin_amdgcn_mfma_f32_16x16x32_bf16(w3, X1, a3, 0, 0, 0);
                float ev;
                ev  = fast_tanh(a0[0]) * w2c[0][0];
                ev += fast_tanh(a0[1]) * w2c[0][1];
                ev += fast_tanh(a0[2]) * w2c[0][2];
                ev += fast_tanh(a0[3]) * w2c[0][3];
                ev += fast_tanh(a1[0]) * w2c[1][0];
                ev += fast_tanh(a1[1]) * w2c[1][1];
                ev += fast_tanh(a1[2]) * w2c[1][2];
                ev += fast_tanh(a1[3]) * w2c[1][3];
                ev += fast_tanh(a2[0]) * w2c[2][0];
                ev += fast_tanh(a2[1]) * w2c[2][1];
                ev += fast_tanh(a2[2]) * w2c[2][2];
                ev += fast_tanh(a2[3]) * w2c[2][3];
                ev += fast_tanh(a3[0]) * w2c[3][0];
                ev += fast_tanh(a3[1]) * w2c[3][1];
                ev += fast_tanh(a3[2]) * w2c[3][2];
                ev += fast_tanh(a3[3]) * w2c[3][3];
                ev += __shfl_xor(ev, 16);
                ev += __shfl_xor(ev, 32);
                if (lane < 16) atomicAdd(&out[iaCur], ev + b2v);
                tB = tN;
                liveB = haveN;
            }
            if (!liveA) break;
        }
    }
done:
    return;
#undef STAGE_BODY
}

extern "C" void kernel_launch(void* const* d_in, const int* in_sizes, int n_in,
                              void* d_out, int out_size, void* d_ws, size_t ws_size,
                              hipStream_t stream) {
    Params p;
    for (int e = 0; e < 3; ++e) {
        p.e[e].x   = (const float*)d_in[6 * e + 0];
        p.e[e].idx = (const int*)  d_in[6 * e + 1];
        p.e[e].W1  = (const float*)d_in[6 * e + 2];
        p.e[e].b1  = (const float*)d_in[6 * e + 3];
        p.e[e].W2  = (const float*)d_in[6 * e + 4];
        p.e[e].b2  = (const float*)d_in[6 * e + 5];
    }
    const int n_atoms = in_sizes[0] / 64;
    p.n_tiles = n_atoms / 16;   // 62,500

    float* out = (float*)d_out;
    // d_out is poisoned (0xAA) before timing and NOT re-zeroed between replays.
    hipMemsetAsync(out, 0, (size_t)out_size * sizeof(float), stream);

    // 683x3 = 2049 blocks ~ 8 blocks/CU available; residency reg-capped at ~4/CU.
    dim3 grid(683, 3);
    atom_mlp<<<grid, 256, 0, stream>>>(p, out);
}